// Round 1
// 4879.491 us; speedup vs baseline: 1.0712x; 1.0712x over previous
//
#include <hip/hip_runtime.h>
#include <math.h>

#define N 64
#define CSTR 68   // column stride (floats): 272B = 17*16B -> b128-aligned, bank-balanced

typedef float f32x2 __attribute__((ext_vector_type(2)));

struct __align__(16) Smem {
    float mat[N * CSTR];   // column-major: mat[c*CSTR + r] = M[r][c]
    float nbuf[2 * N];     // per-sweep norm partials
    f32x2 obuf[2][N];      // pair-dot partials (x=wave0, y=wave1), parity-buffered
};

__device__ __forceinline__ float bperm(int byteaddr, float v) {
    return __int_as_float(__builtin_amdgcn_ds_bpermute(byteaddr, __float_as_int(v)));
}
__device__ __forceinline__ float rlane(float v, int k) {   // uniform k -> v_readlane (VALU)
    return __int_as_float(__builtin_amdgcn_readlane(__float_as_int(v), k));
}
__device__ __forceinline__ float dot4(float4 a, float4 b) {
    return fmaf(a.x, b.x, fmaf(a.y, b.y, fmaf(a.z, b.z, a.w * b.w)));
}

// One-sided Jacobi; matrix columns live in LDS (column-major, stride CSTR).
// Wave w owns rows [32w,32w+32): lane j holds that half of column j in g[8].
// Partner-column halves fetched via ds_read_b128 (16B/lane/inst, ~4x bpermute
// bandwidth); updated halves written back the same way. Each wave touches only
// its own row range, so no cross-wave LDS hazard in the loop; pair dots are
// completed via obuf partials with both waves summing in the same order ->
// o/d/c/s streams bitwise-identical -> uniform branches.
//
// Thresholds: rotation/convergence at o^2 > 4e-10*dp*dq (rel 2e-5) -- safely
// above the fp32 dot-product noise floor (~5e-7 rel typical); the old 1e-11
// sat AT the noise floor and let pairs flicker "bad" forever. Predictive
// break: if a whole sweep stays below o^2 <= 1e-7*dp*dq (angles <= 3e-4),
// next-sweep fill-in is quadratically small -> skip the confirm sweep.
__device__ float jacobi_b128(float4 (&g)[8], int lane, int wid, Smem& S, int max_sweeps) {
    float4* ownc = (float4*)&S.mat[lane * CSTR + 32 * wid];
    float d = 0.f;
#pragma clang loop unroll(disable)
    for (int s = 0; s < max_sweeps; ++s) {
        float nh = 0.f;
#pragma unroll
        for (int i = 0; i < 8; ++i) nh += dot4(g[i], g[i]);
        S.nbuf[wid * N + lane] = nh;
        __syncthreads();
        d = S.nbuf[lane] + S.nbuf[N + lane];
        int anybad = 0, anybig = 0;
#pragma clang loop unroll(disable)
        for (int m = 1; m < N; ++m) {
            const float4* pc = (const float4*)&S.mat[(lane ^ m) * CSTR + 32 * wid];
            float4 t[8];
#pragma unroll
            for (int i = 0; i < 8; ++i) t[i] = pc[i];
            float op = 0.f;
#pragma unroll
            for (int i = 0; i < 8; ++i) op += dot4(g[i], t[i]);
            float doth = bperm((lane ^ m) << 2, d);
            int p = m & 1;
            ((float*)&S.obuf[p][lane])[wid] = op;
            __syncthreads();
            f32x2 ov = S.obuf[p][lane];
            float o = ov.x + ov.y;           // same order on both waves
            bool is_lo = lane < (lane ^ m);
            float dp = is_lo ? d : doth;
            float dq = is_lo ? doth : d;
            float oo = o * o, pq = dp * dq;
            int roundbad = __any(oo > 4e-10f * pq);
            anybad |= roundbad;
            anybig |= __any(oo > 1e-7f * pq);
            if (!roundbad) continue;         // uniform: converged round, no write-back
            bool skip = oo <= (1e-24f * pq);
            float osafe = skip ? 1.0f : o;
            float theta = (dq - dp) * 0.5f * __builtin_amdgcn_rcpf(osafe);
            float tt = -copysignf(
                __builtin_amdgcn_rcpf(fabsf(theta) + sqrtf(fmaf(theta, theta, 1.0f))),
                theta);
            float cc = rsqrtf(fmaf(tt, tt, 1.0f));
            float sv = tt * cc;
            cc = skip ? 1.0f : cc;
            sv = skip ? 0.0f : sv;
            float c2 = cc * cc, s2 = sv * sv, cso = 2.0f * cc * sv * o;
            d = is_lo ? fmaf(c2, dp, fmaf(s2, dq, cso))
                      : fmaf(s2, dp, fmaf(c2, dq, -cso));
            d = fmaxf(d, 1e-30f);
            float ss = is_lo ? sv : -sv;
#pragma unroll
            for (int i = 0; i < 8; ++i) {
                g[i].x = fmaf(ss, t[i].x, cc * g[i].x);
                g[i].y = fmaf(ss, t[i].y, cc * g[i].y);
                g[i].z = fmaf(ss, t[i].z, cc * g[i].z);
                g[i].w = fmaf(ss, t[i].w, cc * g[i].w);
            }
#pragma unroll
            for (int i = 0; i < 8; ++i) ownc[i] = g[i];
        }
        if (!__any(anybad) || !anybig) break;   // uniform across both waves
    }
    float nh = 0.f;
#pragma unroll
    for (int i = 0; i < 8; ++i) nh += dot4(g[i], g[i]);
    S.nbuf[wid * N + lane] = nh;
    __syncthreads();
    d = S.nbuf[lane] + S.nbuf[N + lane];
    return d;
}

// out rows [32w,+32), column `lane`: out = sum_k coef_k g_k g_k^T.
// All broadcasts via v_readlane (VALU pipe) -- only DS is the 64 b32 row reads.
__device__ void recon_store(const float4 (&g)[8], float coef, int lane, int wid,
                            Smem& S, float* __restrict__ outp) {
    int row0 = wid * 32;
    float4 acc[8];
#pragma unroll
    for (int i = 0; i < 8; ++i) acc[i] = (float4){0.f, 0.f, 0.f, 0.f};
#pragma clang loop unroll(disable)
    for (int k = 0; k < N; ++k) {
        float wk = rlane(coef, k) * S.mat[k * CSTR + lane];   // coef_k * G[lane][k]
#pragma unroll
        for (int i = 0; i < 8; ++i) {
            acc[i].x = fmaf(rlane(g[i].x, k), wk, acc[i].x);
            acc[i].y = fmaf(rlane(g[i].y, k), wk, acc[i].y);
            acc[i].z = fmaf(rlane(g[i].z, k), wk, acc[i].z);
            acc[i].w = fmaf(rlane(g[i].w, k), wk, acc[i].w);
        }
    }
#pragma unroll
    for (int i = 0; i < 8; ++i) {
        outp[(row0 + 4 * i + 0) * N + lane] = acc[i].x;
        outp[(row0 + 4 * i + 1) * N + lane] = acc[i].y;
        outp[(row0 + 4 * i + 2) * N + lane] = acc[i].z;
        outp[(row0 + 4 * i + 3) * N + lane] = acc[i].w;
    }
}

// Kernel A: R_c = ((1-psi) W_c + psi I)^{-1/2}; one block (2 waves) per channel.
__global__ __launch_bounds__(128, 4) void prep_R(const float* __restrict__ wgt,
                                                 float* __restrict__ Rws) {
    __shared__ Smem S;
    int c = blockIdx.x;
    int tid = threadIdx.x, wid = tid >> 6, lane = tid & 63;
    int row0 = wid * 32;
    const float* W = wgt + (size_t)c * (N * N);
    float4 g[8];
#pragma unroll
    for (int i = 0; i < 8; ++i) {
        float v[4];
#pragma unroll
        for (int q = 0; q < 4; ++q) {
            int rr = row0 + 4 * i + q;
            v[q] = 0.999f * W[rr * N + lane] + (rr == lane ? 0.001f : 0.f);
        }
        g[i] = (float4){v[0], v[1], v[2], v[3]};
    }
    float4* ownc = (float4*)&S.mat[lane * CSTR + row0];
#pragma unroll
    for (int i = 0; i < 8; ++i) ownc[i] = g[i];
    float d = jacobi_b128(g, lane, wid, S, 15);
    float coef = sqrtf(rsqrtf(d)) / d;   // f = lambda^{-1/2} -> coef = d^{-5/4}
    recon_store(g, coef, lane, wid, S, Rws + (size_t)c * (N * N));
}

// Kernel B: per (b,c): M = R_c Theta_b R_c -> symmetrize -> recondition -> log.
__global__ __launch_bounds__(128, 4) void tangent_log(const float* __restrict__ inp,
                                                      const float* __restrict__ Rws,
                                                      float* __restrict__ out) {
    __shared__ Smem S;
    int bid = blockIdx.x, b = bid >> 2, c = bid & 3;
    int tid = threadIdx.x, wid = tid >> 6, lane = tid & 63;
    int row0 = wid * 32;
    const float* Th = inp + (size_t)b * (N * N);
    const float* Rc = Rws + (size_t)c * (N * N);

    // r = full column `lane` of R (coalesced b32 loads)
    f32x2 r[32];
#pragma unroll
    for (int k = 0; k < 32; ++k) {
        r[k].x = Rc[(2 * k) * N + lane];
        r[k].y = Rc[(2 * k + 1) * N + lane];
    }
    // U = Theta * R : rows [row0,+32), column `lane` -> LDS (column-major)
#pragma clang loop unroll(disable)
    for (int i = 0; i < 32; ++i) {
        const float4* __restrict__ row = (const float4*)(Th + (size_t)(row0 + i) * N);
        f32x2 a = {0.f, 0.f}, bacc = {0.f, 0.f};
#pragma unroll
        for (int q = 0; q < 16; q += 2) {
            float4 v0 = row[q], v1 = row[q + 1];
            a    = (f32x2){v0.x, v0.y} * r[2 * q]     + a;
            a    = (f32x2){v0.z, v0.w} * r[2 * q + 1] + a;
            bacc = (f32x2){v1.x, v1.y} * r[2 * q + 2] + bacc;
            bacc = (f32x2){v1.z, v1.w} * r[2 * q + 3] + bacc;
        }
        f32x2 sres = a + bacc;
        S.mat[lane * CSTR + row0 + i] = sres.x + sres.y;
    }
    __syncthreads();
    // ucol = full column `lane` of U (contiguous in column-major -> b128 reads)
    f32x2 ucol[32];
    {
        const f32x2* myc = (const f32x2*)&S.mat[lane * CSTR];
#pragma unroll
        for (int k = 0; k < 32; ++k) ucol[k] = myc[k];
    }
    __syncthreads();   // all U reads done before overwrite
    // M = R * U : rows [row0,+32), column `lane` -> overwrite LDS
#pragma clang loop unroll(disable)
    for (int i = 0; i < 32; ++i) {
        const float4* __restrict__ row = (const float4*)(Rc + (size_t)(row0 + i) * N);
        f32x2 a = {0.f, 0.f}, bacc = {0.f, 0.f};
#pragma unroll
        for (int q = 0; q < 16; q += 2) {
            float4 v0 = row[q], v1 = row[q + 1];
            a    = (f32x2){v0.x, v0.y} * ucol[2 * q]     + a;
            a    = (f32x2){v0.z, v0.w} * ucol[2 * q + 1] + a;
            bacc = (f32x2){v1.x, v1.y} * ucol[2 * q + 2] + bacc;
            bacc = (f32x2){v1.z, v1.w} * ucol[2 * q + 3] + bacc;
        }
        f32x2 sres = a + bacc;
        S.mat[lane * CSTR + row0 + i] = sres.x + sres.y;
    }
    __syncthreads();
    // g = 0.5*(M + M^T) half-column + convex recondition
    float4 g[8];
    {
        float4 own[8];
        const float4* oc = (const float4*)&S.mat[lane * CSTR + row0];
#pragma unroll
        for (int i = 0; i < 8; ++i) own[i] = oc[i];
        float tr[32];
#pragma unroll
        for (int i = 0; i < 32; ++i) tr[i] = S.mat[(row0 + i) * CSTR + lane];  // M[lane][row0+i]
        __syncthreads();   // all reads done before write-back
#pragma unroll
        for (int i = 0; i < 8; ++i) {
            float v[4];
#pragma unroll
            for (int q = 0; q < 4; ++q) {
                int rr = row0 + 4 * i + q;
                float ov = (q == 0) ? own[i].x : (q == 1) ? own[i].y : (q == 2) ? own[i].z : own[i].w;
                float sym = 0.5f * (ov + tr[4 * i + q]);
                v[q] = 0.999f * sym + (rr == lane ? 0.001f : 0.f);
            }
            g[i] = (float4){v[0], v[1], v[2], v[3]};
        }
        float4* wc = (float4*)&S.mat[lane * CSTR + row0];
#pragma unroll
        for (int i = 0; i < 8; ++i) wc[i] = g[i];
    }

    float d = jacobi_b128(g, lane, wid, S, 15);
    float coef = 0.5f * logf(d) / d;   // f = log(lambda) = 0.5*log(d)
    recon_store(g, coef, lane, wid, S, out + (size_t)bid * (N * N));
}

extern "C" void kernel_launch(void* const* d_in, const int* in_sizes, int n_in,
                              void* d_out, int out_size, void* d_ws, size_t ws_size,
                              hipStream_t stream) {
    const float* inp = (const float*)d_in[0];   // [B,64,64] f32
    const float* wgt = (const float*)d_in[1];   // [C,64,64] f32
    float* out = (float*)d_out;                 // [B,C,64,64] f32
    float* Rws = (float*)d_ws;                  // C*64*64 floats scratch

    int B = in_sizes[0] / (N * N);
    int C = in_sizes[1] / (N * N);

    hipLaunchKernelGGL(prep_R, dim3(C), dim3(128), 0, stream, wgt, Rws);
    hipLaunchKernelGGL(tangent_log, dim3(B * C), dim3(128), 0, stream, inp, Rws, out);
}

// Round 2
// 4649.699 us; speedup vs baseline: 1.1241x; 1.0494x over previous
//
#include <hip/hip_runtime.h>
#include <math.h>

#define N 64
#define CSTR 68   // column stride (floats): 272 B = 17*16 B -> b128-aligned; bank floor 8-pass

typedef float f32x2 __attribute__((ext_vector_type(2)));

__device__ __forceinline__ float bperm(int byteaddr, float v) {
    return __int_as_float(__builtin_amdgcn_ds_bpermute(byteaddr, __float_as_int(v)));
}
__device__ __forceinline__ float rlane(float v, int k) {   // uniform k -> v_readlane
    return __int_as_float(__builtin_amdgcn_readlane(__float_as_int(v), k));
}
__device__ __forceinline__ f32x2 lo2(float4 v) { return (f32x2){v.x, v.y}; }
__device__ __forceinline__ f32x2 hi2(float4 v) { return (f32x2){v.z, v.w}; }
__device__ __forceinline__ float4 join4(f32x2 a, f32x2 b) { return (float4){a.x, a.y, b.x, b.y}; }
__device__ __forceinline__ f32x2 pkfma(f32x2 a, f32x2 b, f32x2 c) {   // v_pk_fma_f32
    return __builtin_elementwise_fma(a, b, c);
}

// One-sided Jacobi, ONE WAVE PER MATRIX. Lane j holds the full 64-elem column j
// in g[16] (float4). Matrix mirrored in this wave's private LDS region
// (column-major, stride CSTR). Partner column fetched via 16x ds_read_b128;
// updated column written back the same way. No __syncthreads anywhere: all
// cross-lane exchange is same-wave LDS (lgkmcnt-ordered) or bpermute.
// Pair-dot o computed redundantly on both partner lanes with identical
// accumulation order -> bitwise-identical -> uniform rotation decisions.
__device__ float jacobi_wave(float4 (&g)[16], int lane, float* __restrict__ mat,
                             int max_sweeps) {
    float4* __restrict__ ownc = (float4*)&mat[lane * CSTR];
    float d = 0.f;
#pragma clang loop unroll(disable)
    for (int s = 0; s < max_sweeps; ++s) {
        {   // d = ||col||^2, fully in-lane (no exchange needed)
            f32x2 na = {0.f, 0.f}, nb = {0.f, 0.f};
#pragma unroll
            for (int i = 0; i < 16; ++i) {
                na = pkfma(lo2(g[i]), lo2(g[i]), na);
                nb = pkfma(hi2(g[i]), hi2(g[i]), nb);
            }
            f32x2 ns = na + nb;
            d = ns.x + ns.y;
        }
        int anybad = 0, anybig = 0;
#pragma clang loop unroll(disable)
        for (int m = 1; m < N; ++m) {
            const float4* __restrict__ pc = (const float4*)&mat[(lane ^ m) * CSTR];
            float4 t[16];
#pragma unroll
            for (int i = 0; i < 16; ++i) t[i] = pc[i];
            // o = g . t ; 4 accumulators, order identical on both partner lanes
            f32x2 oa = {0.f, 0.f}, ob = {0.f, 0.f}, oc = {0.f, 0.f}, od = {0.f, 0.f};
#pragma unroll
            for (int i = 0; i < 8; ++i) {
                oa = pkfma(lo2(g[2 * i]),     lo2(t[2 * i]),     oa);
                ob = pkfma(hi2(g[2 * i]),     hi2(t[2 * i]),     ob);
                oc = pkfma(lo2(g[2 * i + 1]), lo2(t[2 * i + 1]), oc);
                od = pkfma(hi2(g[2 * i + 1]), hi2(t[2 * i + 1]), od);
            }
            f32x2 os = (oa + ob) + (oc + od);
            float o = os.x + os.y;
            float doth = bperm((lane ^ m) << 2, d);
            bool is_lo = lane < (lane ^ m);
            float dp = is_lo ? d : doth;
            float dq = is_lo ? doth : d;
            float oo = o * o, pq = dp * dq;
            int roundbad = __any(oo > 4e-10f * pq);
            anybad |= roundbad;
            anybig |= __any(oo > 1e-7f * pq);
            if (!roundbad) continue;         // wave-uniform: no write-back this step
            bool skip = oo <= (1e-24f * pq);
            float osafe = skip ? 1.0f : o;
            float theta = (dq - dp) * 0.5f * __builtin_amdgcn_rcpf(osafe);
            float tt = -copysignf(
                __builtin_amdgcn_rcpf(fabsf(theta) + sqrtf(fmaf(theta, theta, 1.0f))),
                theta);
            float cc = rsqrtf(fmaf(tt, tt, 1.0f));
            float sv = tt * cc;
            cc = skip ? 1.0f : cc;
            sv = skip ? 0.0f : sv;
            float c2 = cc * cc, s2 = sv * sv, cso = 2.0f * cc * sv * o;
            d = is_lo ? fmaf(c2, dp, fmaf(s2, dq, cso))
                      : fmaf(s2, dp, fmaf(c2, dq, -cso));
            d = fmaxf(d, 1e-30f);
            float ss = is_lo ? sv : -sv;
            f32x2 cc2 = {cc, cc}, ss2 = {ss, ss};
#pragma unroll
            for (int i = 0; i < 16; ++i) {   // packed update + fused write-back
                f32x2 glo = pkfma(ss2, lo2(t[i]), lo2(g[i]) * cc2);
                f32x2 ghi = pkfma(ss2, hi2(t[i]), hi2(g[i]) * cc2);
                g[i] = join4(glo, ghi);
                ownc[i] = g[i];
            }
        }
        if (!anybad || !anybig) break;   // both wave-uniform
    }
    f32x2 na = {0.f, 0.f}, nb = {0.f, 0.f};
#pragma unroll
    for (int i = 0; i < 16; ++i) {
        na = pkfma(lo2(g[i]), lo2(g[i]), na);
        nb = pkfma(hi2(g[i]), hi2(g[i]), nb);
    }
    f32x2 ns = na + nb;
    return ns.x + ns.y;
}

// out[:,lane] = sum_k coef_k G[:,k] * G[lane][k]. Broadcasts via v_readlane;
// only DS traffic is the 64 b32 per-lane reads of G[lane][k] (2-way, free).
__device__ void recon_store(const float4 (&g)[16], float coef, int lane,
                            const float* __restrict__ mat, float* __restrict__ outp) {
    f32x2 acc[32];
#pragma unroll
    for (int i = 0; i < 32; ++i) acc[i] = (f32x2){0.f, 0.f};
#pragma clang loop unroll(disable)
    for (int k = 0; k < N; ++k) {
        float wk = rlane(coef, k) * mat[k * CSTR + lane];   // coef_k * G[lane][k]
        f32x2 wk2 = {wk, wk};
#pragma unroll
        for (int i = 0; i < 16; ++i) {
            f32x2 b0 = {rlane(g[i].x, k), rlane(g[i].y, k)};
            f32x2 b1 = {rlane(g[i].z, k), rlane(g[i].w, k)};
            acc[2 * i]     = pkfma(b0, wk2, acc[2 * i]);
            acc[2 * i + 1] = pkfma(b1, wk2, acc[2 * i + 1]);
        }
    }
#pragma unroll
    for (int i = 0; i < 32; ++i) {
        outp[(size_t)(2 * i) * N + lane]     = acc[i].x;
        outp[(size_t)(2 * i + 1) * N + lane] = acc[i].y;
    }
}

// Kernel A: R_c = ((1-psi) W_c + psi I)^{-1/2}; one WAVE per channel.
__global__ __launch_bounds__(128, 2) void prep_R(const float* __restrict__ wgt,
                                                 float* __restrict__ Rws, int C) {
    __shared__ float S[2][N * CSTR];
    int tid = threadIdx.x, wid = tid >> 6, lane = tid & 63;
    int c = blockIdx.x * 2 + wid;
    if (c >= C) return;
    c = __builtin_amdgcn_readfirstlane(c);
    const float* __restrict__ W = wgt + (size_t)c * (N * N);
    float* __restrict__ mat = S[wid];
    float4 g[16];
#pragma unroll
    for (int i = 0; i < 16; ++i) {
        float v0 = 0.999f * W[(4 * i + 0) * N + lane] + ((4 * i + 0) == lane ? 0.001f : 0.f);
        float v1 = 0.999f * W[(4 * i + 1) * N + lane] + ((4 * i + 1) == lane ? 0.001f : 0.f);
        float v2 = 0.999f * W[(4 * i + 2) * N + lane] + ((4 * i + 2) == lane ? 0.001f : 0.f);
        float v3 = 0.999f * W[(4 * i + 3) * N + lane] + ((4 * i + 3) == lane ? 0.001f : 0.f);
        g[i] = (float4){v0, v1, v2, v3};
    }
    float4* __restrict__ ownc = (float4*)&mat[lane * CSTR];
#pragma unroll
    for (int i = 0; i < 16; ++i) ownc[i] = g[i];
    float d = jacobi_wave(g, lane, mat, 15);
    float coef = sqrtf(rsqrtf(d)) / d;   // f = lambda^{-1/2} -> coef = d^{-5/4}
    recon_store(g, coef, lane, mat, Rws + (size_t)c * (N * N));
}

// Kernel B: per (b,c): M = R_c Theta_b R_c -> symmetrize -> recondition -> log.
// One WAVE per (b,c); congruence fully in registers (U and M columns are
// lane-local); LDS touched only for the symmetrize transpose + Jacobi mirror.
__global__ __launch_bounds__(128, 2) void tangent_log(const float* __restrict__ inp,
                                                      const float* __restrict__ Rws,
                                                      float* __restrict__ out, int total) {
    __shared__ float S[2][N * CSTR];
    int tid = threadIdx.x, wid = tid >> 6, lane = tid & 63;
    int midx = blockIdx.x * 2 + wid;
    if (midx >= total) return;
    midx = __builtin_amdgcn_readfirstlane(midx);   // SGPR-uniform matrix pointers
    int b = midx >> 2, c = midx & 3;
    const float* __restrict__ Th = inp + (size_t)b * (N * N);
    const float* __restrict__ Rc = Rws + (size_t)c * (N * N);
    float* __restrict__ mat = S[wid];

    // r = column `lane` of R (R symmetric; coalesced b32 loads)
    f32x2 r[32];
#pragma unroll
    for (int k = 0; k < 32; ++k)
        r[k] = (f32x2){Rc[(2 * k) * N + lane], Rc[(2 * k + 1) * N + lane]};

    // ucol = (Theta * R)[:, lane] -- stays in registers
    f32x2 ucol[32];
#pragma clang loop unroll(disable)
    for (int i = 0; i < 32; ++i) {
        const float4* __restrict__ r0 = (const float4*)(Th + (size_t)(2 * i) * N);
        const float4* __restrict__ r1 = (const float4*)(Th + (size_t)(2 * i + 1) * N);
        f32x2 a0 = {0.f, 0.f}, b0 = {0.f, 0.f}, a1 = {0.f, 0.f}, b1 = {0.f, 0.f};
#pragma unroll
        for (int q = 0; q < 16; ++q) {
            float4 v0 = r0[q], v1 = r1[q];
            a0 = pkfma(lo2(v0), r[2 * q], a0);
            b0 = pkfma(hi2(v0), r[2 * q + 1], b0);
            a1 = pkfma(lo2(v1), r[2 * q], a1);
            b1 = pkfma(hi2(v1), r[2 * q + 1], b1);
        }
        f32x2 s0 = a0 + b0, s1 = a1 + b1;
        ucol[i] = (f32x2){s0.x + s0.y, s1.x + s1.y};
    }
    // mcol = (R * U)[:, lane] -- stays in registers
    f32x2 mcol[32];
#pragma clang loop unroll(disable)
    for (int i = 0; i < 32; ++i) {
        const float4* __restrict__ r0 = (const float4*)(Rc + (size_t)(2 * i) * N);
        const float4* __restrict__ r1 = (const float4*)(Rc + (size_t)(2 * i + 1) * N);
        f32x2 a0 = {0.f, 0.f}, b0 = {0.f, 0.f}, a1 = {0.f, 0.f}, b1 = {0.f, 0.f};
#pragma unroll
        for (int q = 0; q < 16; ++q) {
            float4 v0 = r0[q], v1 = r1[q];
            a0 = pkfma(lo2(v0), ucol[2 * q], a0);
            b0 = pkfma(hi2(v0), ucol[2 * q + 1], b0);
            a1 = pkfma(lo2(v1), ucol[2 * q], a1);
            b1 = pkfma(hi2(v1), ucol[2 * q + 1], b1);
        }
        f32x2 s0 = a0 + b0, s1 = a1 + b1;
        mcol[i] = (f32x2){s0.x + s0.y, s1.x + s1.y};
    }
    // stash M column in LDS; transpose-read (same-wave, lgkmcnt-ordered);
    // symmetrize + recondition -> g; write g as the Jacobi working matrix
    float4* __restrict__ ownc = (float4*)&mat[lane * CSTR];
#pragma unroll
    for (int i = 0; i < 16; ++i) ownc[i] = join4(mcol[2 * i], mcol[2 * i + 1]);
    float4 g[16];
#pragma unroll
    for (int i = 0; i < 16; ++i) {
        float t0 = mat[(4 * i + 0) * CSTR + lane];   // M[lane][4i+q] via other lanes' cols
        float t1 = mat[(4 * i + 1) * CSTR + lane];
        float t2 = mat[(4 * i + 2) * CSTR + lane];
        float t3 = mat[(4 * i + 3) * CSTR + lane];
        f32x2 mlo = mcol[2 * i], mhi = mcol[2 * i + 1];
        float4 vv;
        vv.x = 0.999f * (0.5f * (mlo.x + t0)) + ((4 * i + 0) == lane ? 0.001f : 0.f);
        vv.y = 0.999f * (0.5f * (mlo.y + t1)) + ((4 * i + 1) == lane ? 0.001f : 0.f);
        vv.z = 0.999f * (0.5f * (mhi.x + t2)) + ((4 * i + 2) == lane ? 0.001f : 0.f);
        vv.w = 0.999f * (0.5f * (mhi.y + t3)) + ((4 * i + 3) == lane ? 0.001f : 0.f);
        g[i] = vv;
    }
#pragma unroll
    for (int i = 0; i < 16; ++i) ownc[i] = g[i];

    float d = jacobi_wave(g, lane, mat, 15);
    float coef = 0.5f * logf(d) / d;   // f = log(lambda) = 0.5*log(d)
    recon_store(g, coef, lane, mat, out + (size_t)midx * (N * N));
}

extern "C" void kernel_launch(void* const* d_in, const int* in_sizes, int n_in,
                              void* d_out, int out_size, void* d_ws, size_t ws_size,
                              hipStream_t stream) {
    const float* inp = (const float*)d_in[0];   // [B,64,64] f32
    const float* wgt = (const float*)d_in[1];   // [C,64,64] f32
    float* out = (float*)d_out;                 // [B,C,64,64] f32
    float* Rws = (float*)d_ws;                  // C*64*64 floats scratch

    int B = in_sizes[0] / (N * N);
    int C = in_sizes[1] / (N * N);

    hipLaunchKernelGGL(prep_R, dim3((C + 1) / 2), dim3(128), 0, stream, wgt, Rws, C);
    hipLaunchKernelGGL(tangent_log, dim3((B * C + 1) / 2), dim3(128), 0, stream,
                       inp, Rws, out, B * C);
}